// Round 16
// baseline (4318.498 us; speedup 1.0000x reference)
//
#include <hip/hip_runtime.h>
#include <hip/hip_fp16.h>
#include <stdint.h>

// GNN: 2x SAGEConv(mean)+ReLU + mean-pool + linear, algebraically refactored:
//  te = emb@W1l^T (fp16 gather table), trb = emb@W1r^T + b1 (fp32)
//  k_g1ec : EDGE-CENTRIC conv1 gather: stream edges, LDS fp32 accumulate by
//           dst; h1 = relu(acc/deg + trb[x[n]]) (fp16)
//  k_gemm : g1 = h1@W2l^T (fp16); s1 = h1@W2r^T + b2 (fp32)  [MFMA 16x16x32]
//  k_c2ec : EDGE-CENTRIC conv2: stream edges, gather g1[src], LDS accumulate;
//           o[n] = relu(acc/deg + s1[n]) @ Wout^T
//  k_pool : out[g] = mean(o) + bout
// pairs[pos] = uint2{ (src<<8)|dloc, x[src] } in bucket regions (NBUCK=1024,
// <=196 nodes/bucket -> 52KB LDS acc, 3 blocks/CU x 8 waves = 75% occupancy
// BY CONSTRUCTION). Edge-centric removes the per-node serial RT chain that
// capped R12-R15's per-node gather kernels (~5600cyc/node).

#define NPB 4
#define NBUCK 1024
#define MAXNN 200   // >= ceil(n_nodes/NBUCK) = 196
#define ASTRIDE 65  // acc row stride (floats): spreads banks across dloc

typedef __attribute__((ext_vector_type(8))) _Float16 half8;
typedef __attribute__((ext_vector_type(4))) float f32x4;

__global__ void k_init(int* __restrict__ gcur, int cap) {
  gcur[threadIdx.x] = threadIdx.x * cap;  // 1024 threads
}

// 512 thr, TILE=8192 (EPT=16): 8-edge runs x 8B = 64B granule writes.
// 4-way sub-hist (g = t>>7) cuts LDS atomic contention.
__global__ void k_part(const int* __restrict__ src, const int* __restrict__ dst,
                       const int* __restrict__ x, int* __restrict__ gcur,
                       uint2* __restrict__ pairs, int n_edges, int n_nodes, int chunk) {
  __shared__ int hist[NBUCK * 4];
  __shared__ int base[NBUCK * 4];
  int t = threadIdx.x;
  int g = t >> 7;
  int beg = blockIdx.x * chunk;
  int end = min(beg + chunk, n_edges);
  for (int tbeg = beg; tbeg < end; tbeg += 8192) {
    int cnt = min(8192, end - tbeg);
    for (int i = t; i < NBUCK * 4; i += 512) hist[i] = 0;
    __syncthreads();
    unsigned lo[16], hi[16];
    int r[16], bk[16];
    bool v[16];
#pragma unroll
    for (int k = 0; k < 16; ++k) {
      int li = k * 512 + t;
      v[k] = li < cnt;
      if (v[k]) {
        int i = tbeg + li;
        int s = src[i];
        int d = dst[i];
        bk[k] = (int)(((unsigned)d * 1024u) / (unsigned)n_nodes);
        unsigned nb0 = ((unsigned)bk[k] * (unsigned)n_nodes + 1023u) >> 10;
        lo[k] = ((unsigned)s << 8) | ((unsigned)d - nb0);
        hi[k] = (unsigned)x[s];
        r[k] = atomicAdd(&hist[bk[k] * 4 + g], 1);
      }
    }
    __syncthreads();
    for (int b = t; b < NBUCK; b += 512) {
      int h0 = hist[b * 4 + 0], h1 = hist[b * 4 + 1];
      int h2 = hist[b * 4 + 2], h3 = hist[b * 4 + 3];
      int tot = h0 + h1 + h2 + h3;
      int b0 = (tot > 0) ? atomicAdd(&gcur[b], tot) : 0;
      base[b * 4 + 0] = b0;
      base[b * 4 + 1] = b0 + h0;
      base[b * 4 + 2] = b0 + h0 + h1;
      base[b * 4 + 3] = b0 + h0 + h1 + h2;
    }
    __syncthreads();
#pragma unroll
    for (int k = 0; k < 16; ++k)
      if (v[k]) pairs[base[bk[k] * 4 + g] + r[k]] = make_uint2(lo[k], hi[k]);
    __syncthreads();
  }
}

__global__ void k_transpose4(const float* __restrict__ a0, const float* __restrict__ a1,
                             const float* __restrict__ a2, const float* __restrict__ a3,
                             float* __restrict__ wt) {
  const float* s = (blockIdx.x == 0) ? a0 : (blockIdx.x == 1) ? a1 : (blockIdx.x == 2) ? a2 : a3;
  float* d = wt + blockIdx.x * 4096;
  for (int i = threadIdx.x; i < 4096; i += blockDim.x) {
    int r = i >> 6, c = i & 63;
    d[c * 64 + r] = s[i];
  }
}

// pack W2l,W2r into MFMA B-fragment order (same k-map as A: k=(l>>4)*8+j)
__global__ void k_packB(const float* __restrict__ W2l, const float* __restrict__ W2r,
                        __half* __restrict__ pB) {
  int i = blockIdx.x * 256 + threadIdx.x;
  if (i >= 8192) return;
  int j = i & 7, l = (i >> 3) & 63, kt = (i >> 9) & 1, nt = (i >> 10) & 3, mat = i >> 12;
  int k = kt * 32 + (l >> 4) * 8 + j;
  int n = nt * 16 + (l & 15);
  const float* W = mat ? W2r : W2l;
  pB[i] = __float2half(W[n * 64 + k]);
}

__global__ void k_prep(const float* __restrict__ emb, const float* __restrict__ w1lT,
                       const float* __restrict__ w1rT, const float* __restrict__ b1,
                       __half* __restrict__ te, float* __restrict__ trb, int vocab) {
  __shared__ float se[NPB][64];
  int wid = threadIdx.x >> 6, lane = threadIdx.x & 63;
  int v = blockIdx.x * NPB + wid;
  if (v >= vocab) return;
  se[wid][lane] = emb[(size_t)v * 64 + lane];
  __syncwarp();
  float aL = 0.f, aR = b1[lane];
#pragma unroll 8
  for (int f = 0; f < 64; ++f) {
    float ev = se[wid][f];
    aL = fmaf(ev, w1lT[f * 64 + lane], aL);
    aR = fmaf(ev, w1rT[f * 64 + lane], aR);
  }
  te[(size_t)v * 64 + lane] = __float2half(aL);
  trb[(size_t)v * 64 + lane] = aR;
}

// per 8-row batch: guarded load (row index from shfl'd pair word) ...
#define ELD(J, IDXEXPR, TBL) \
  int dl##J = 0; bool m##J = false; uint4 u##J; \
  if (J < ng) { \
    int kk = J * 8 + r8; \
    int sl = min(kk, nit - 1); \
    unsigned pl = __shfl(eLo, sl); \
    unsigned ph = __shfl(eHi, sl); (void)ph; \
    dl##J = (int)(pl & 0xFFu); \
    m##J = kk < nit; \
    unsigned ridx = (IDXEXPR); \
    u##J = *(const uint4*)(TBL + ((size_t)ridx << 6) + s8); \
  }
// ... then LDS fp32 atomic accumulate (8 rows x 64 feats) + deg count
#define EACC(J) \
  if (m##J) { \
    const __half2* hp = (const __half2*)&u##J; \
    float* ap = &acc[dl##J * ASTRIDE + s8]; \
    _Pragma("unroll") \
    for (int q = 0; q < 4; ++q) { \
      float2 f = __half22float2(hp[q]); \
      atomicAdd(ap + 2 * q, f.x); \
      atomicAdd(ap + 2 * q + 1, f.y); \
    } \
    if ((lane & 7) == 0) atomicAdd(&cnt[dl##J], 1); \
  }

// edge-centric conv1 gather: bucket block, LDS accumulate te rows by dloc;
// h1 = relu(acc/deg + trb[x[node]]) (fp16)
__global__ __launch_bounds__(512) void
k_g1ec(const uint2* __restrict__ pairs, const int* __restrict__ gcur,
       const __half* __restrict__ te, const float* __restrict__ trb,
       const int* __restrict__ x, __half* __restrict__ h1,
       int n_nodes, int cap) {
  __shared__ float acc[MAXNN * ASTRIDE];
  __shared__ int cnt[MAXNN];
  int b = blockIdx.x, t = threadIdx.x;
  int lane = t & 63, wid = t >> 6;
  int r8 = lane >> 3, s8 = (lane & 7) << 3;
  int nb0 = (int)(((unsigned)b * (unsigned)n_nodes + 1023u) >> 10);
  int nb1 = (int)(((unsigned)(b + 1) * (unsigned)n_nodes + 1023u) >> 10);
  if (nb1 > n_nodes) nb1 = n_nodes;
  int nn = nb1 - nb0;
  for (int i = t; i < MAXNN * ASTRIDE; i += 512) acc[i] = 0.f;
  for (int i = t; i < nn; i += 512) cnt[i] = 0;
  __syncthreads();
  int rend = gcur[b];
  for (int cbase = b * cap + wid * 64; cbase < rend; cbase += 512) {
    int nit = min(64, rend - cbase);
    uint2 e = pairs[cbase + min(lane, nit - 1)];
    unsigned eLo = e.x, eHi = e.y;
    int ng = (nit + 7) >> 3;
    ELD(0, ph, te) ELD(1, ph, te) ELD(2, ph, te) ELD(3, ph, te)
    ELD(4, ph, te) ELD(5, ph, te) ELD(6, ph, te) ELD(7, ph, te)
    EACC(0) EACC(1) EACC(2) EACC(3) EACC(4) EACC(5) EACC(6) EACC(7)
  }
  __syncthreads();
  for (int i = wid; i < nn; i += 8) {
    float v = acc[i * ASTRIDE + lane];
    int dg = cnt[i];
    float inv = (dg > 0) ? 1.f / (float)dg : 0.f;
    int xv = x[nb0 + i];
    float tb = trb[((size_t)xv << 6) + lane];
    float h = fmaxf(fmaf(v, inv, tb), 0.f);
    h1[((size_t)(nb0 + i) << 6) + lane] = __float2half(h);
  }
}

// MFMA mini-GEMM: [16 nodes x 64] @ {W2l^T, W2r^T} -> g1 (fp16), s1 (fp32, +b2)
__global__ __launch_bounds__(64) void
k_gemm(const __half* __restrict__ h1, const __half* __restrict__ pB,
       const float* __restrict__ b2, __half* __restrict__ g1,
       float* __restrict__ s1, int n_nodes) {
  int lane = threadIdx.x;
  int nbase = blockIdx.x * 16;
  int row = lane & 15, grp = lane >> 4;
  const half8 a0 = *(const half8*)(h1 + ((size_t)(nbase + row) << 6) + grp * 8);
  const half8 a1 = *(const half8*)(h1 + ((size_t)(nbase + row) << 6) + 32 + grp * 8);
#pragma unroll
  for (int t = 0; t < 8; ++t) {
    const half8 b0 = *(const half8*)(pB + (t * 2 + 0) * 512 + lane * 8);
    const half8 b1 = *(const half8*)(pB + (t * 2 + 1) * 512 + lane * 8);
    f32x4 acc = {0.f, 0.f, 0.f, 0.f};
    acc = __builtin_amdgcn_mfma_f32_16x16x32_f16(a0, b0, acc, 0, 0, 0);
    acc = __builtin_amdgcn_mfma_f32_16x16x32_f16(a1, b1, acc, 0, 0, 0);
    int out = (t & 3) * 16 + (lane & 15);
    if (t < 4) {
#pragma unroll
      for (int r = 0; r < 4; ++r) {
        int node = nbase + grp * 4 + r;
        if (node < n_nodes) g1[((size_t)node << 6) + out] = __float2half(acc[r]);
      }
    } else {
      float bias = b2[out];
#pragma unroll
      for (int r = 0; r < 4; ++r) {
        int node = nbase + grp * 4 + r;
        if (node < n_nodes) s1[((size_t)node << 6) + out] = acc[r] + bias;
      }
    }
  }
}

// edge-centric conv2: LDS accumulate g1[src] rows by dloc;
// o[node] = relu(acc/deg + s1[node]) @ Wout^T
__global__ __launch_bounds__(512) void
k_c2ec(const uint2* __restrict__ pairs, const int* __restrict__ gcur,
       const __half* __restrict__ g1, const float* __restrict__ s1,
       const float* __restrict__ wout, float* __restrict__ o,
       int n_nodes, int cap) {
  __shared__ float acc[MAXNN * ASTRIDE];
  __shared__ int cnt[MAXNN];
  int b = blockIdx.x, t = threadIdx.x;
  int lane = t & 63, wid = t >> 6;
  int r8 = lane >> 3, s8 = (lane & 7) << 3;
  int nb0 = (int)(((unsigned)b * (unsigned)n_nodes + 1023u) >> 10);
  int nb1 = (int)(((unsigned)(b + 1) * (unsigned)n_nodes + 1023u) >> 10);
  if (nb1 > n_nodes) nb1 = n_nodes;
  int nn = nb1 - nb0;
  for (int i = t; i < MAXNN * ASTRIDE; i += 512) acc[i] = 0.f;
  for (int i = t; i < nn; i += 512) cnt[i] = 0;
  __syncthreads();
  float w0 = wout[lane], w1v = wout[64 + lane];
  int rend = gcur[b];
  for (int cbase = b * cap + wid * 64; cbase < rend; cbase += 512) {
    int nit = min(64, rend - cbase);
    uint2 e = pairs[cbase + min(lane, nit - 1)];
    unsigned eLo = e.x, eHi = e.y;
    (void)eHi;
    int ng = (nit + 7) >> 3;
    ELD(0, (pl >> 8) & 0x3FFFFu, g1) ELD(1, (pl >> 8) & 0x3FFFFu, g1)
    ELD(2, (pl >> 8) & 0x3FFFFu, g1) ELD(3, (pl >> 8) & 0x3FFFFu, g1)
    ELD(4, (pl >> 8) & 0x3FFFFu, g1) ELD(5, (pl >> 8) & 0x3FFFFu, g1)
    ELD(6, (pl >> 8) & 0x3FFFFu, g1) ELD(7, (pl >> 8) & 0x3FFFFu, g1)
    EACC(0) EACC(1) EACC(2) EACC(3) EACC(4) EACC(5) EACC(6) EACC(7)
  }
  __syncthreads();
  for (int i = wid; i < nn; i += 8) {
    float v = acc[i * ASTRIDE + lane];
    int dg = cnt[i];
    float inv = (dg > 0) ? 1.f / (float)dg : 0.f;
    int node = nb0 + i;
    float h2 = fmaxf(v * inv + s1[((size_t)node << 6) + lane], 0.f);
    float p0 = h2 * w0;
    float p1 = h2 * w1v;
    for (int off = 32; off > 0; off >>= 1) {
      p0 += __shfl_down(p0, off);
      p1 += __shfl_down(p1, off);
    }
    if (lane == 0) {
      o[((size_t)node << 1) + 0] = p0;
      o[((size_t)node << 1) + 1] = p1;
    }
  }
}

__global__ void k_goffs(const int* __restrict__ batch, int* __restrict__ goffs,
                        int n_nodes, int n_graphs) {
  int i = blockIdx.x * blockDim.x + threadIdx.x;
  if (i >= n_nodes) return;
  int b = batch[i];
  int bp = (i == 0) ? -1 : batch[i - 1];
  for (int g = bp + 1; g <= b; ++g) goffs[g] = i;
  if (i == n_nodes - 1)
    for (int g = b + 1; g <= n_graphs; ++g) goffs[g] = n_nodes;
}

__global__ void k_pool(const float2* __restrict__ o, const int* __restrict__ goffs,
                       const float* __restrict__ bout, float* __restrict__ out,
                       int n_graphs) {
  int wid = threadIdx.x >> 6, lane = threadIdx.x & 63;
  int g = blockIdx.x * NPB + wid;
  if (g >= n_graphs) return;
  int beg = goffs[g], end = goffs[g + 1];
  float a0 = 0.f, a1 = 0.f;
  for (int n = beg + lane; n < end; n += 64) {
    float2 v = o[n];
    a0 += v.x;
    a1 += v.y;
  }
  for (int off = 32; off > 0; off >>= 1) {
    a0 += __shfl_down(a0, off);
    a1 += __shfl_down(a1, off);
  }
  if (lane == 0) {
    int cntg = end - beg;
    float inv = (cntg > 0) ? 1.f / (float)cntg : 0.f;
    out[g * 2 + 0] = a0 * inv + bout[0];
    out[g * 2 + 1] = a1 * inv + bout[1];
  }
}

extern "C" void kernel_launch(void* const* d_in, const int* in_sizes, int n_in,
                              void* d_out, int out_size, void* d_ws, size_t ws_size,
                              hipStream_t stream) {
  const int* x = (const int*)d_in[0];
  const int* ei = (const int*)d_in[1];
  const int* batch = (const int*)d_in[2];
  const float* emb = (const float*)d_in[3];
  const float* W1l = (const float*)d_in[4];
  const float* b1 = (const float*)d_in[5];
  const float* W1r = (const float*)d_in[6];
  const float* W2l = (const float*)d_in[7];
  const float* b2 = (const float*)d_in[8];
  const float* W2r = (const float*)d_in[9];
  const float* Wout = (const float*)d_in[10];
  const float* bout = (const float*)d_in[11];
  float* out = (float*)d_out;

  int n_nodes = in_sizes[0];
  int n_edges = in_sizes[1] / 2;
  int vocab = in_sizes[3] / 64;
  int n_graphs = out_size / 2;
  const int* src = ei;
  const int* dst = ei + n_edges;

  // per-bucket region capacity: mean 6250, sigma ~79 -> huge margin
  int cap = n_edges / NBUCK + n_edges / (NBUCK * 8) + 512;
  int ntiles = (n_nodes + 15) / 16;

  char* p = (char*)d_ws;
  auto alloc = [&](size_t bytes) -> void* {
    void* r = (void*)p;
    p += (bytes + 255) & ~(size_t)255;
    return r;
  };
  __half* te = (__half*)alloc((size_t)vocab * 64 * 2);
  float* trb = (float*)alloc((size_t)vocab * 64 * 4);
  float* wt = (float*)alloc(2 * 4096 * 4);
  __half* pB = (__half*)alloc(8192 * 2);
  int* goffs = (int*)alloc((size_t)(n_graphs + 1) * 4);
  int* gcur = (int*)alloc(NBUCK * 4);
  uint2* pairs = (uint2*)alloc((size_t)NBUCK * cap * 8);  // bucket-sparse, lives to conv2
  __half* h1 = (__half*)alloc((size_t)(ntiles * 16) * 64 * 2);
  __half* g1 = (__half*)alloc((size_t)n_nodes * 64 * 2);
  float* s1 = (float*)alloc((size_t)n_nodes * 64 * 4);
  float* o = (float*)alloc((size_t)n_nodes * 2 * 4);

  k_init<<<1, NBUCK, 0, stream>>>(gcur, cap);
  k_packB<<<32, 256, 0, stream>>>(W2l, W2r, pB);
  k_transpose4<<<2, 256, 0, stream>>>(W1l, W1r, W1l, W1l, wt);
  k_prep<<<(vocab + NPB - 1) / NPB, 64 * NPB, 0, stream>>>(emb, wt, wt + 4096, b1, te, trb, vocab);

  int part_blocks = 512;
  int chunk = (n_edges + part_blocks - 1) / part_blocks;
  k_part<<<part_blocks, 512, 0, stream>>>(src, dst, x, gcur, pairs, n_edges, n_nodes, chunk);

  k_goffs<<<(n_nodes + 255) / 256, 256, 0, stream>>>(batch, goffs, n_nodes, n_graphs);

  k_g1ec<<<NBUCK, 512, 0, stream>>>(pairs, gcur, te, trb, x, h1, n_nodes, cap);
  k_gemm<<<ntiles, 64, 0, stream>>>(h1, pB, b2, g1, s1, n_nodes);
  k_c2ec<<<NBUCK, 512, 0, stream>>>(pairs, gcur, g1, s1, Wout, o, n_nodes, cap);
  k_pool<<<(n_graphs + NPB - 1) / NPB, 64 * NPB, 0, stream>>>((const float2*)o, goffs, bout, out, n_graphs);
}

// Round 17
// 398.402 us; speedup vs baseline: 10.8396x; 10.8396x over previous
//
#include <hip/hip_runtime.h>
#include <hip/hip_fp16.h>
#include <stdint.h>

// GNN: 2x SAGEConv(mean)+ReLU + mean-pool + linear, algebraically refactored:
//  te = emb@W1l^T (fp16 gather table), trb = emb@W1r^T + b1 (fp32)
//  k_gather1: h1 = relu(mean(te[x[src]]) + trb[x[n]])          (fp16)
//  k_gemm   : g1 = h1@W2l^T (fp16); s1 = h1@W2r^T + b2 (fp32)  [MFMA 16x16x32]
//  k_conv2  : h2 = relu(mean(g1[src]) + s1[n]); o[n] = h2@Wout^T
//  k_pool   : out[g] = mean(o) + bout
// idx[pos] = (x[src]<<18) | src, stored bucket-SPARSE (cap-strided regions);
// per-node obeg/oend point into it (no dense compaction scan).
// Conv/gather: 1 node/wave, VGPR 36, occ ~70% — the measured optimum.
// CLOSED ARMS (all regressions): NPW=8 (R9, VGPR cliff), 2-node/wave (R14,
// occ 43%), edge-centric LDS-float-atomics (R16, 10x: serialized ds RMW chain).

#define NPB 4
#define NBUCK 256
#define TILE 4096
#define EPT 16
#define MAXN 1024

typedef __attribute__((ext_vector_type(8))) _Float16 half8;
typedef __attribute__((ext_vector_type(4))) float f32x4;

__device__ __forceinline__ int bucket_of(int dstv, int n_nodes) {
  return (int)(((unsigned)dstv * 256u) / (unsigned)n_nodes);
}

// masked accumulate
__device__ __forceinline__ void acc8h(float* a, uint4 u, float m) {
  const __half2* hp = (const __half2*)&u;
#pragma unroll
  for (int q = 0; q < 4; ++q) {
    float2 f = __half22float2(hp[q]);
    a[2 * q]     = fmaf(m, f.x, a[2 * q]);
    a[2 * q + 1] = fmaf(m, f.y, a[2 * q + 1]);
  }
}

// unmasked accumulate
__device__ __forceinline__ void add8(float* a, uint4 u) {
  const __half2* hp = (const __half2*)&u;
#pragma unroll
  for (int q = 0; q < 4; ++q) {
    float2 f = __half22float2(hp[q]);
    a[2 * q]     += f.x;
    a[2 * q + 1] += f.y;
  }
}

// LDS-tile multisplit with 4-way sub-histograms (per-wave)
__global__ void k_part(const int* __restrict__ src, const int* __restrict__ dst,
                       int* __restrict__ gcur, unsigned* __restrict__ pairs,
                       int n_edges, int n_nodes, int chunk) {
  __shared__ int hist[NBUCK * 4];
  __shared__ int base[NBUCK * 4];
  int t = threadIdx.x;
  int g = t >> 6;
  int beg = blockIdx.x * chunk;
  int end = min(beg + chunk, n_edges);
  for (int tbeg = beg; tbeg < end; tbeg += TILE) {
    int cnt = min(TILE, end - tbeg);
    hist[t] = 0; hist[t + 256] = 0; hist[t + 512] = 0; hist[t + 768] = 0;
    __syncthreads();
    unsigned pk[EPT];
    int r[EPT], bk[EPT];
    bool v[EPT];
#pragma unroll
    for (int k = 0; k < EPT; ++k) {
      int li = k * 256 + t;
      v[k] = li < cnt;
      if (v[k]) {
        int i = tbeg + li;
        int s = src[i];
        int d = dst[i];
        bk[k] = bucket_of(d, n_nodes);
        unsigned nb0 = ((unsigned)bk[k] * (unsigned)n_nodes + 255u) >> 8;
        pk[k] = (((unsigned)d - nb0) << 18) | (unsigned)s;
        r[k] = atomicAdd(&hist[bk[k] * 4 + g], 1);
      }
    }
    __syncthreads();
    int h0 = hist[t * 4 + 0], h1 = hist[t * 4 + 1];
    int h2 = hist[t * 4 + 2], h3 = hist[t * 4 + 3];
    int tot = h0 + h1 + h2 + h3;
    int b0 = (tot > 0) ? atomicAdd(&gcur[t], tot) : 0;
    base[t * 4 + 0] = b0;
    base[t * 4 + 1] = b0 + h0;
    base[t * 4 + 2] = b0 + h0 + h1;
    base[t * 4 + 3] = b0 + h0 + h1 + h2;
    __syncthreads();
#pragma unroll
    for (int k = 0; k < EPT; ++k)
      if (v[k]) pairs[base[bk[k] * 4 + g] + r[k]] = pk[k];
    __syncthreads();
  }
}

// one block per bucket: LDS node-hist -> scan -> obeg/oend (into SPARSE idx);
// scatter packed (x[src]<<18|src) into the bucket's own region.
__global__ void k_bucket(const unsigned* __restrict__ pairs, const int* __restrict__ gcur,
                         const int* __restrict__ x, int* __restrict__ obeg,
                         int* __restrict__ oend, unsigned* __restrict__ idx,
                         int n_nodes, int cap) {
  __shared__ int lcnt[MAXN];
  __shared__ int lcur[MAXN];
  __shared__ int stmp[256];
  int b = blockIdx.x, t = threadIdx.x;
  int nb0 = (int)((((unsigned)b * (unsigned)n_nodes) + 255u) >> 8);
  int nb1 = (int)((((unsigned)(b + 1) * (unsigned)n_nodes) + 255u) >> 8);
  if (nb1 > n_nodes) nb1 = n_nodes;
  int nn = nb1 - nb0;
  int rbeg = b * cap;
  int rend = gcur[b];
  for (int i = t; i < nn; i += 256) lcnt[i] = 0;
  __syncthreads();
  for (int i = rbeg + t; i < rend; i += 256)
    atomicAdd(&lcnt[pairs[i] >> 18], 1);
  __syncthreads();
  int i0 = t * 4;
  int v0 = (i0 + 0 < nn) ? lcnt[i0 + 0] : 0;
  int v1 = (i0 + 1 < nn) ? lcnt[i0 + 1] : 0;
  int v2 = (i0 + 2 < nn) ? lcnt[i0 + 2] : 0;
  int v3 = (i0 + 3 < nn) ? lcnt[i0 + 3] : 0;
  stmp[t] = v0 + v1 + v2 + v3;
  __syncthreads();
  for (int off = 1; off < 256; off <<= 1) {
    int add = (t >= off) ? stmp[t - off] : 0;
    __syncthreads();
    stmp[t] += add;
    __syncthreads();
  }
  int run = rbeg + ((t == 0) ? 0 : stmp[t - 1]);
  if (i0 + 0 < nn) { lcur[i0 + 0] = run; obeg[nb0 + i0 + 0] = run; oend[nb0 + i0 + 0] = run + v0; run += v0; }
  if (i0 + 1 < nn) { lcur[i0 + 1] = run; obeg[nb0 + i0 + 1] = run; oend[nb0 + i0 + 1] = run + v1; run += v1; }
  if (i0 + 2 < nn) { lcur[i0 + 2] = run; obeg[nb0 + i0 + 2] = run; oend[nb0 + i0 + 2] = run + v2; run += v2; }
  if (i0 + 3 < nn) { lcur[i0 + 3] = run; obeg[nb0 + i0 + 3] = run; oend[nb0 + i0 + 3] = run + v3; run += v3; }
  __syncthreads();
  for (int i = rbeg + t; i < rend; i += 256) {
    unsigned e = pairs[i];
    int s = (int)(e & 0x3FFFFu);
    int pos = atomicAdd(&lcur[e >> 18], 1);
    idx[pos] = ((unsigned)x[s] << 18) | (unsigned)s;
  }
}

__global__ void k_transpose4(const float* __restrict__ a0, const float* __restrict__ a1,
                             const float* __restrict__ a2, const float* __restrict__ a3,
                             float* __restrict__ wt) {
  const float* s = (blockIdx.x == 0) ? a0 : (blockIdx.x == 1) ? a1 : (blockIdx.x == 2) ? a2 : a3;
  float* d = wt + blockIdx.x * 4096;
  for (int i = threadIdx.x; i < 4096; i += blockDim.x) {
    int r = i >> 6, c = i & 63;
    d[c * 64 + r] = s[i];
  }
}

// pack W2l,W2r into MFMA B-fragment order (same k-map as A: k=(l>>4)*8+j)
// + folds cursor init (block 0).
__global__ void k_packB(const float* __restrict__ W2l, const float* __restrict__ W2r,
                        __half* __restrict__ pB, int* __restrict__ gcur, int cap) {
  if (blockIdx.x == 0) gcur[threadIdx.x] = threadIdx.x * cap;
  int i = blockIdx.x * 256 + threadIdx.x;
  if (i >= 8192) return;
  int j = i & 7, l = (i >> 3) & 63, kt = (i >> 9) & 1, nt = (i >> 10) & 3, mat = i >> 12;
  int k = kt * 32 + (l >> 4) * 8 + j;
  int n = nt * 16 + (l & 15);
  const float* W = mat ? W2r : W2l;
  pB[i] = __float2half(W[n * 64 + k]);
}

__global__ void k_prep(const float* __restrict__ emb, const float* __restrict__ w1lT,
                       const float* __restrict__ w1rT, const float* __restrict__ b1,
                       __half* __restrict__ te, float* __restrict__ trb, int vocab) {
  __shared__ float se[NPB][64];
  int wid = threadIdx.x >> 6, lane = threadIdx.x & 63;
  int v = blockIdx.x * NPB + wid;
  if (v >= vocab) return;
  se[wid][lane] = emb[(size_t)v * 64 + lane];
  __syncwarp();
  float aL = 0.f, aR = b1[lane];
#pragma unroll 8
  for (int f = 0; f < 64; ++f) {
    float ev = se[wid][f];
    aL = fmaf(ev, w1lT[f * 64 + lane], aL);
    aR = fmaf(ev, w1rT[f * 64 + lane], aR);
  }
  te[(size_t)v * 64 + lane] = __float2half(aL);
  trb[(size_t)v * 64 + lane] = aR;
}

// gather + mean + trb + relu -> h1 (fp16); all chunk loads issued before acc
__global__ __launch_bounds__(64, 6) void
k_gather1(const unsigned* __restrict__ idx, const int* __restrict__ obeg,
          const int* __restrict__ oend, const __half* __restrict__ te,
          const float* __restrict__ trb, const int* __restrict__ x,
          __half* __restrict__ h1, int n_nodes) {
  int lane = threadIdx.x;
  int r8 = lane >> 3, s8 = (lane & 7) << 3;
  int node = blockIdx.x;
  if (node >= n_nodes) return;
  int xv = x[node];                    // hoisted (feeds trb much later)
  int beg = obeg[node], end = oend[node];
  float a[8];
#pragma unroll
  for (int q = 0; q < 8; ++q) a[q] = 0.f;
  for (int c = beg; c < end; c += 64) {
    int nit = min(end - c, 64);
    unsigned eidx = idx[c + min(lane, nit - 1)];
    int ngrp = (nit + 7) >> 3;
    int nfg = nit >> 3;
    uint4 u0, u1, u2, u3, u4, u5, u6, u7;
#define CLD1(J) if (J < ngrp) { \
      int vv = (int)(__shfl(eidx, min(J * 8 + r8, nit - 1)) >> 18); \
      u##J = *(const uint4*)(te + ((size_t)vv << 6) + s8); }
    CLD1(0) CLD1(1) CLD1(2) CLD1(3) CLD1(4) CLD1(5) CLD1(6) CLD1(7)
#undef CLD1
#define CACC1(J) if (J < nfg) add8(a, u##J); \
    else if (J < ngrp) acc8h(a, u##J, (J * 8 + r8 < nit) ? 1.f : 0.f);
    CACC1(0) CACC1(1) CACC1(2) CACC1(3) CACC1(4) CACC1(5) CACC1(6) CACC1(7)
#undef CACC1
  }
  // issue trb rows before the reduce so their latency hides under it
  float4 t0, t1;
  if (lane < 8) {
    const float* tp = trb + ((size_t)xv << 6) + s8;
    t0 = *(const float4*)tp;
    t1 = *(const float4*)(tp + 4);
  }
#pragma unroll
  for (int q = 0; q < 8; ++q) {
    a[q] += __shfl_xor(a[q], 8);
    a[q] += __shfl_xor(a[q], 16);
    a[q] += __shfl_xor(a[q], 32);
  }
  int deg = end - beg;
  float inv = (deg > 0) ? 1.f / (float)deg : 0.f;
  if (lane < 8) {
    __half hh[8];
    hh[0] = __float2half(fmaxf(fmaf(a[0], inv, t0.x), 0.f));
    hh[1] = __float2half(fmaxf(fmaf(a[1], inv, t0.y), 0.f));
    hh[2] = __float2half(fmaxf(fmaf(a[2], inv, t0.z), 0.f));
    hh[3] = __float2half(fmaxf(fmaf(a[3], inv, t0.w), 0.f));
    hh[4] = __float2half(fmaxf(fmaf(a[4], inv, t1.x), 0.f));
    hh[5] = __float2half(fmaxf(fmaf(a[5], inv, t1.y), 0.f));
    hh[6] = __float2half(fmaxf(fmaf(a[6], inv, t1.z), 0.f));
    hh[7] = __float2half(fmaxf(fmaf(a[7], inv, t1.w), 0.f));
    *(uint4*)(h1 + ((size_t)node << 6) + s8) = *(uint4*)hh;
  }
}

// MFMA mini-GEMM: [16 nodes x 64] @ {W2l^T, W2r^T} -> g1 (fp16), s1 (fp32, +b2)
__global__ __launch_bounds__(64) void
k_gemm(const __half* __restrict__ h1, const __half* __restrict__ pB,
       const float* __restrict__ b2, __half* __restrict__ g1,
       float* __restrict__ s1, int n_nodes) {
  int lane = threadIdx.x;
  int nbase = blockIdx.x * 16;
  int row = lane & 15, grp = lane >> 4;
  const half8 a0 = *(const half8*)(h1 + ((size_t)(nbase + row) << 6) + grp * 8);
  const half8 a1 = *(const half8*)(h1 + ((size_t)(nbase + row) << 6) + 32 + grp * 8);
#pragma unroll
  for (int t = 0; t < 8; ++t) {
    const half8 b0 = *(const half8*)(pB + (t * 2 + 0) * 512 + lane * 8);
    const half8 b1 = *(const half8*)(pB + (t * 2 + 1) * 512 + lane * 8);
    f32x4 acc = {0.f, 0.f, 0.f, 0.f};
    acc = __builtin_amdgcn_mfma_f32_16x16x32_f16(a0, b0, acc, 0, 0, 0);
    acc = __builtin_amdgcn_mfma_f32_16x16x32_f16(a1, b1, acc, 0, 0, 0);
    int out = (t & 3) * 16 + (lane & 15);
    if (t < 4) {
#pragma unroll
      for (int r = 0; r < 4; ++r) {
        int node = nbase + grp * 4 + r;
        if (node < n_nodes) g1[((size_t)node << 6) + out] = __float2half(acc[r]);
      }
    } else {
      float bias = b2[out];
#pragma unroll
      for (int r = 0; r < 4; ++r) {
        int node = nbase + grp * 4 + r;
        if (node < n_nodes) s1[((size_t)node << 6) + out] = acc[r] + bias;
      }
    }
  }
}

// conv2: gather g1 + mean + s1 + relu -> o = h2@Wout^T; RT-chain optimized
__global__ __launch_bounds__(64, 6) void
k_conv2(const unsigned* __restrict__ idx, const int* __restrict__ obeg,
        const int* __restrict__ oend, const __half* __restrict__ g1,
        const float* __restrict__ s1, const float* __restrict__ wout,
        float* __restrict__ o, int n_nodes) {
  __shared__ float sm[64];
  int lane = threadIdx.x;
  int r8 = lane >> 3, s8 = (lane & 7) << 3;
  int node = blockIdx.x;
  if (node >= n_nodes) return;
  float s1v = s1[((size_t)node << 6) + lane];   // hoisted off critical path
  float w0 = wout[lane], w1v = wout[64 + lane]; // hoisted
  int beg = obeg[node], end = oend[node];
  float a[8];
#pragma unroll
  for (int q = 0; q < 8; ++q) a[q] = 0.f;
  for (int c = beg; c < end; c += 64) {
    int nit = min(end - c, 64);
    unsigned eidx = idx[c + min(lane, nit - 1)];
    int ngrp = (nit + 7) >> 3;
    int nfg = nit >> 3;
    uint4 u0, u1, u2, u3, u4, u5, u6, u7;
#define CLD2(J) if (J < ngrp) { \
      int vv = (int)(__shfl(eidx, min(J * 8 + r8, nit - 1)) & 0x3FFFFu); \
      u##J = *(const uint4*)(g1 + ((size_t)vv << 6) + s8); }
    CLD2(0) CLD2(1) CLD2(2) CLD2(3) CLD2(4) CLD2(5) CLD2(6) CLD2(7)
#undef CLD2
#define CACC2(J) if (J < nfg) add8(a, u##J); \
    else if (J < ngrp) acc8h(a, u##J, (J * 8 + r8 < nit) ? 1.f : 0.f);
    CACC2(0) CACC2(1) CACC2(2) CACC2(3) CACC2(4) CACC2(5) CACC2(6) CACC2(7)
#undef CACC2
  }
#pragma unroll
  for (int q = 0; q < 8; ++q) {
    a[q] += __shfl_xor(a[q], 8);
    a[q] += __shfl_xor(a[q], 16);
    a[q] += __shfl_xor(a[q], 32);
  }
  int deg = end - beg;
  float inv = (deg > 0) ? 1.f / (float)deg : 0.f;
  if (lane < 8) {
#pragma unroll
    for (int q = 0; q < 8; ++q) sm[s8 + q] = a[q] * inv;
  }
  __syncthreads();
  float h2 = fmaxf(sm[lane] + s1v, 0.f);
  float p0 = h2 * w0;
  float p1 = h2 * w1v;
  for (int off = 32; off > 0; off >>= 1) {
    p0 += __shfl_down(p0, off);
    p1 += __shfl_down(p1, off);
  }
  if (lane == 0) {
    o[((size_t)node << 1) + 0] = p0;
    o[((size_t)node << 1) + 1] = p1;
  }
}

__global__ void k_goffs(const int* __restrict__ batch, int* __restrict__ goffs,
                        int n_nodes, int n_graphs) {
  int i = blockIdx.x * blockDim.x + threadIdx.x;
  if (i >= n_nodes) return;
  int b = batch[i];
  int bp = (i == 0) ? -1 : batch[i - 1];
  for (int g = bp + 1; g <= b; ++g) goffs[g] = i;
  if (i == n_nodes - 1)
    for (int g = b + 1; g <= n_graphs; ++g) goffs[g] = n_nodes;
}

__global__ void k_pool(const float2* __restrict__ o, const int* __restrict__ goffs,
                       const float* __restrict__ bout, float* __restrict__ out,
                       int n_graphs) {
  int wid = threadIdx.x >> 6, lane = threadIdx.x & 63;
  int g = blockIdx.x * NPB + wid;
  if (g >= n_graphs) return;
  int beg = goffs[g], end = goffs[g + 1];
  float a0 = 0.f, a1 = 0.f;
  for (int n = beg + lane; n < end; n += 64) {
    float2 v = o[n];
    a0 += v.x;
    a1 += v.y;
  }
  for (int off = 32; off > 0; off >>= 1) {
    a0 += __shfl_down(a0, off);
    a1 += __shfl_down(a1, off);
  }
  if (lane == 0) {
    int cnt = end - beg;
    float inv = (cnt > 0) ? 1.f / (float)cnt : 0.f;
    out[g * 2 + 0] = a0 * inv + bout[0];
    out[g * 2 + 1] = a1 * inv + bout[1];
  }
}

extern "C" void kernel_launch(void* const* d_in, const int* in_sizes, int n_in,
                              void* d_out, int out_size, void* d_ws, size_t ws_size,
                              hipStream_t stream) {
  const int* x = (const int*)d_in[0];
  const int* ei = (const int*)d_in[1];
  const int* batch = (const int*)d_in[2];
  const float* emb = (const float*)d_in[3];
  const float* W1l = (const float*)d_in[4];
  const float* b1 = (const float*)d_in[5];
  const float* W1r = (const float*)d_in[6];
  const float* W2l = (const float*)d_in[7];
  const float* b2 = (const float*)d_in[8];
  const float* W2r = (const float*)d_in[9];
  const float* Wout = (const float*)d_in[10];
  const float* bout = (const float*)d_in[11];
  float* out = (float*)d_out;

  int n_nodes = in_sizes[0];
  int n_edges = in_sizes[1] / 2;
  int vocab = in_sizes[3] / 64;
  int n_graphs = out_size / 2;
  const int* src = ei;
  const int* dst = ei + n_edges;

  int cap = n_edges / NBUCK + n_edges / (NBUCK * 8) + 1024;
  int ntiles = (n_nodes + 15) / 16;

  char* p = (char*)d_ws;
  auto alloc = [&](size_t bytes) -> void* {
    void* r = (void*)p;
    p += (bytes + 255) & ~(size_t)255;
    return r;
  };
  __half* te = (__half*)alloc((size_t)vocab * 64 * 2);
  float* trb = (float*)alloc((size_t)vocab * 64 * 4);
  float* wt = (float*)alloc(2 * 4096 * 4);
  __half* pB = (__half*)alloc(8192 * 2);
  int* obeg = (int*)alloc((size_t)n_nodes * 4);
  int* oend = (int*)alloc((size_t)n_nodes * 4);
  int* goffs = (int*)alloc((size_t)(n_graphs + 1) * 4);
  int* gcur = (int*)alloc(NBUCK * 4);
  unsigned* idx = (unsigned*)alloc((size_t)NBUCK * cap * 4);  // bucket-sparse
  __half* h1 = (__half*)alloc((size_t)(ntiles * 16) * 64 * 2);
  size_t pairs_bytes = (size_t)NBUCK * cap * 4;
  size_t g1_bytes = (size_t)n_nodes * 64 * 2;
  unsigned* pairs = (unsigned*)alloc(pairs_bytes > g1_bytes ? pairs_bytes : g1_bytes);
  float* s1 = (float*)alloc((size_t)n_nodes * 64 * 4);
  float* o = (float*)alloc((size_t)n_nodes * 2 * 4);
  __half* g1 = (__half*)pairs;  // pairs dead before k_gemm writes g1

  k_packB<<<32, 256, 0, stream>>>(W2l, W2r, pB, gcur, cap);  // + cursor init
  k_transpose4<<<2, 256, 0, stream>>>(W1l, W1r, W1l, W1l, wt);
  k_prep<<<(vocab + NPB - 1) / NPB, 64 * NPB, 0, stream>>>(emb, wt, wt + 4096, b1, te, trb, vocab);

  int part_blocks = 512;
  int chunk = (n_edges + part_blocks - 1) / part_blocks;
  k_part<<<part_blocks, 256, 0, stream>>>(src, dst, gcur, pairs, n_edges, n_nodes, chunk);
  k_bucket<<<NBUCK, 256, 0, stream>>>(pairs, gcur, x, obeg, oend, idx, n_nodes, cap);

  k_goffs<<<(n_nodes + 255) / 256, 256, 0, stream>>>(batch, goffs, n_nodes, n_graphs);

  k_gather1<<<n_nodes, 64, 0, stream>>>(idx, obeg, oend, te, trb, x, h1, n_nodes);
  k_gemm<<<ntiles, 64, 0, stream>>>(h1, pB, b2, g1, s1, n_nodes);
  k_conv2<<<n_nodes, 64, 0, stream>>>(idx, obeg, oend, g1, s1, Wout, o, n_nodes);
  k_pool<<<(n_graphs + NPB - 1) / NPB, 64 * NPB, 0, stream>>>((const float2*)o, goffs, bout, out, n_graphs);
}